// Round 3
// baseline (4438.788 us; speedup 1.0000x reference)
//
#include <hip/hip_runtime.h>
#include <hip/hip_bf16.h>

// Problem constants
constexpr int B  = 8;
constexpr int T  = 10;
constexpr int HH = 48;
constexpr int WW = 48;
constexpr int F  = 64;     // hidden features
constexpr int CO = 256;    // 4*F gate channels
constexpr int PIX = 16;    // pixels per conv block

// ---------------------------------------------------------------------------
// Tiled direct 3x3 SAME conv: X (B,H,W,CIN) [batch stride] -> out (B,H,W,256).
// ACC=false: out = conv + bias; ACC=true: out += conv.
// Block: 256 threads = one output channel each, PIX consecutive x positions.
// ---------------------------------------------------------------------------
template<int CIN, bool ACC>
__global__ __launch_bounds__(256) void conv3x3_kernel(
    const float* __restrict__ X, long xBatchStride,
    const float* __restrict__ Wt,     // (3,3,CIN,256)
    const float* __restrict__ bias,   // (256) or nullptr when ACC
    float* __restrict__ out)          // (B,H,W,256)
{
    __shared__ float patch[3][PIX + 2][CIN];

    const int bid = blockIdx.x;
    const int bpr = WW / PIX;              // blocks per row = 3
    const int b   = bid / (HH * bpr);
    const int rem = bid % (HH * bpr);
    const int y   = rem / bpr;
    const int x0  = (rem % bpr) * PIX;
    const int tid = threadIdx.x;

    const float* Xb = X + (long)b * xBatchStride;

    // cooperative load of 3 x (PIX+2) x CIN input patch (zero-padded)
    const int total = 3 * (PIX + 2) * CIN;
    for (int e = tid; e < total; e += 256) {
        int ci  = e % CIN;
        int col = (e / CIN) % (PIX + 2);
        int r   = e / (CIN * (PIX + 2));
        int gy  = y + r - 1;
        int gx  = x0 + col - 1;
        float v = 0.f;
        if (gy >= 0 && gy < HH && gx >= 0 && gx < WW)
            v = Xb[((long)gy * WW + gx) * CIN + ci];
        patch[r][col][ci] = v;
    }
    __syncthreads();

    const int co = tid;
    float acc[PIX];
    const float init = ACC ? 0.f : bias[co];
#pragma unroll
    for (int p = 0; p < PIX; ++p) acc[p] = init;

    for (int ky = 0; ky < 3; ++ky) {
        for (int ci4 = 0; ci4 < CIN / 4; ++ci4) {
            float w[3][4];
#pragma unroll
            for (int kx = 0; kx < 3; ++kx)
#pragma unroll
                for (int j = 0; j < 4; ++j)
                    w[kx][j] = Wt[(((ky * 3 + kx) * CIN) + ci4 * 4 + j) * CO + co];
#pragma unroll
            for (int col = 0; col < PIX + 2; ++col) {
                const float4 v = *reinterpret_cast<const float4*>(&patch[ky][col][ci4 * 4]);
#pragma unroll
                for (int kx = 0; kx < 3; ++kx) {
                    const int p = col - kx;
                    if (p >= 0 && p < PIX) {
                        acc[p] += v.x * w[kx][0] + v.y * w[kx][1]
                                + v.z * w[kx][2] + v.w * w[kx][3];
                    }
                }
            }
        }
    }

    float* outp = out + (((long)b * HH + y) * WW + x0) * CO + co;
#pragma unroll
    for (int p = 0; p < PIX; ++p) {
        if (ACC) outp[p * CO] += acc[p];
        else     outp[p * CO]  = acc[p];
    }
}

// ---------------------------------------------------------------------------
// Fused gate / state update.  g: (B,H,W,256) pre-activation gates (i,f,c,o).
// ---------------------------------------------------------------------------
__device__ __forceinline__ float hard_sig(float x) {
    return fminf(fmaxf(0.2f * x + 0.5f, 0.f), 1.f);
}

__global__ __launch_bounds__(256) void lstm_gate_kernel(
    const float* __restrict__ g,
    float* __restrict__ h, float* __restrict__ c,
    float* __restrict__ seqOut,   // nullptr, or seq1 + t*H*W*F
    long seqBatchStride)
{
    const int idx = blockIdx.x * 256 + threadIdx.x;   // < B*H*W*F
    const int f   = idx & 63;
    const int pix = idx >> 6;
    const float* gp = g + (long)pix * CO;

    const float i_ = hard_sig(gp[f]);
    const float f_ = hard_sig(gp[64 + f]);
    const float cc = tanhf(gp[128 + f]);
    const float o_ = hard_sig(gp[192 + f]);

    const float cn = f_ * c[idx] + i_ * cc;
    const float hn = o_ * tanhf(cn);
    c[idx] = cn;
    h[idx] = hn;
    if (seqOut) {
        const int bb  = pix / (HH * WW);
        const int rem = pix % (HH * WW);
        seqOut[(long)bb * seqBatchStride + (long)rem * F + f] = hn;
    }
}

// ---------------------------------------------------------------------------
// BatchNorm (training): per-channel sum / sumsq reduction, then normalize.
// ---------------------------------------------------------------------------
constexpr long SEQ_ELEMS = (long)B * T * HH * WW * F;    // 11,796,480
constexpr float BN_INVN  = 1.0f / (float)(B * T * HH * WW);

__global__ __launch_bounds__(256) void bn_reduce_kernel(
    const float* __restrict__ seq, float* __restrict__ stats /*[128]*/)
{
    const int tid = blockIdx.x * 256 + threadIdx.x;
    const int nthreads = gridDim.x * 256;   // multiple of 64 -> channel fixed per thread
    float s = 0.f, s2 = 0.f;
    for (long i = tid; i < SEQ_ELEMS; i += nthreads) {
        const float v = seq[i];
        s  += v;
        s2 += v * v;
    }
    __shared__ float ls[256], ls2[256];
    ls[threadIdx.x] = s; ls2[threadIdx.x] = s2;
    __syncthreads();
    if (threadIdx.x < 64) {
        const float a = ls[threadIdx.x] + ls[threadIdx.x + 64]
                      + ls[threadIdx.x + 128] + ls[threadIdx.x + 192];
        const float d = ls2[threadIdx.x] + ls2[threadIdx.x + 64]
                      + ls2[threadIdx.x + 128] + ls2[threadIdx.x + 192];
        atomicAdd(&stats[threadIdx.x], a);
        atomicAdd(&stats[64 + threadIdx.x], d);
    }
}

__global__ __launch_bounds__(256) void bn_norm_kernel(
    float* __restrict__ seq, const float* __restrict__ stats,
    const float* __restrict__ gamma, const float* __restrict__ beta)
{
    const long idx = (long)blockIdx.x * 256 + threadIdx.x;
    const int f = (int)(idx & 63);
    const float mean = stats[f] * BN_INVN;
    const float var  = stats[64 + f] * BN_INVN - mean * mean;
    const float sc   = gamma[f] * rsqrtf(var + 1e-3f);
    const float sh   = beta[f] - mean * sc;
    seq[idx] = seq[idx] * sc + sh;
}

// ---------------------------------------------------------------------------
// Final copy: (h1, c1, h2, c2) fp32 -> fp32 d_out   (reference output dtype
// is float32, so d_out is float*)
// ---------------------------------------------------------------------------
constexpr int STATE_ELEMS = B * HH * WW * F;   // 1,179,648

__global__ __launch_bounds__(256) void copy_out_kernel(
    const float* __restrict__ hA, const float* __restrict__ cA,
    const float* __restrict__ hB, const float* __restrict__ cB,
    float* __restrict__ out)
{
    const int idx = blockIdx.x * 256 + threadIdx.x;   // < 4*STATE_ELEMS
    float v;
    if      (idx <     STATE_ELEMS) v = hA[idx];
    else if (idx < 2 * STATE_ELEMS) v = cA[idx - STATE_ELEMS];
    else if (idx < 3 * STATE_ELEMS) v = hB[idx - 2 * STATE_ELEMS];
    else                            v = cB[idx - 3 * STATE_ELEMS];
    out[idx] = v;
}

// ---------------------------------------------------------------------------
extern "C" void kernel_launch(void* const* d_in, const int* in_sizes, int n_in,
                              void* d_out, int out_size, void* d_ws, size_t ws_size,
                              hipStream_t stream)
{
    const float* x      = (const float*)d_in[0];
    const float* Wx1    = (const float*)d_in[1];
    const float* Wh1    = (const float*)d_in[2];
    const float* b1     = (const float*)d_in[3];
    const float* gamma1 = (const float*)d_in[4];
    const float* beta1  = (const float*)d_in[5];
    const float* Wx2    = (const float*)d_in[6];
    const float* Wh2    = (const float*)d_in[7];
    const float* b2     = (const float*)d_in[8];

    // workspace layout (floats)
    float* seq1 = (float*)d_ws;                       // B*T*H*W*F
    float* g    = seq1 + SEQ_ELEMS;                   // B*H*W*256
    float* hA   = g + (long)B * HH * WW * CO;         // states
    float* cA   = hA + STATE_ELEMS;
    float* hB   = cA + STATE_ELEMS;
    float* cB   = hB + STATE_ELEMS;
    float* stats = cB + STATE_ELEMS;                  // 128 floats

    // zero states + stats (contiguous region)
    hipMemsetAsync(hA, 0, (size_t)(4 * STATE_ELEMS + 128) * sizeof(float), stream);

    const int convGrid = B * HH * (WW / PIX);        // 1152
    const int gateGrid = STATE_ELEMS / 256;          // 4608
    const long xTStride   = (long)T * HH * WW * 16;  // x batch stride
    const long seqTStride = (long)T * HH * WW * F;   // seq1 batch stride
    const long hStride    = (long)HH * WW * F;

    // ----- layer 1 -----
    for (int t = 0; t < T; ++t) {
        conv3x3_kernel<16, false><<<convGrid, 256, 0, stream>>>(
            x + (long)t * HH * WW * 16, xTStride, Wx1, b1, g);
        conv3x3_kernel<64, true><<<convGrid, 256, 0, stream>>>(
            hA, hStride, Wh1, nullptr, g);
        lstm_gate_kernel<<<gateGrid, 256, 0, stream>>>(
            g, hA, cA, seq1 + (long)t * HH * WW * F, seqTStride);
    }

    // ----- batchnorm (training) over seq1 -----
    bn_reduce_kernel<<<1024, 256, 0, stream>>>(seq1, stats);
    bn_norm_kernel<<<(int)(SEQ_ELEMS / 256), 256, 0, stream>>>(seq1, stats, gamma1, beta1);

    // ----- layer 2 -----
    for (int t = 0; t < T; ++t) {
        conv3x3_kernel<64, false><<<convGrid, 256, 0, stream>>>(
            seq1 + (long)t * HH * WW * F, seqTStride, Wx2, b2, g);
        conv3x3_kernel<64, true><<<convGrid, 256, 0, stream>>>(
            hB, hStride, Wh2, nullptr, g);
        lstm_gate_kernel<<<gateGrid, 256, 0, stream>>>(
            g, hB, cB, nullptr, 0);
    }

    // ----- output copy (fp32) -----
    copy_out_kernel<<<4 * STATE_ELEMS / 256, 256, 0, stream>>>(
        hA, cA, hB, cB, (float*)d_out);
}

// Round 5
// 432.955 us; speedup vs baseline: 10.2523x; 10.2523x over previous
//
#include <hip/hip_runtime.h>
#include <hip/hip_bf16.h>

typedef short bf16x8 __attribute__((ext_vector_type(8)));   // 8 bf16 in 4 VGPRs
typedef float f32x4  __attribute__((ext_vector_type(4)));

constexpr int B = 8, T = 10, F = 64, CO = 256;
constexpr long IMGPIX      = 48 * 48;                // 2304
constexpr long STATE_ELEMS = (long)B * IMGPIX * F;   // 1,179,648
constexpr long SEQ_ELEMS   = (long)T * STATE_ELEMS;  // 11,796,480
constexpr float BN_INVN    = 1.0f / (float)(B * T * IMGPIX);

__device__ __forceinline__ float  b2f(ushort u) { return __uint_as_float(((unsigned)u) << 16); }
__device__ __forceinline__ ushort f2b(float f) {
    unsigned x = __float_as_uint(f);
    return (ushort)((x + 0x7fffu + ((x >> 16) & 1u)) >> 16);   // RNE
}
__device__ __forceinline__ float hsig(float x) { return fminf(fmaxf(0.2f * x + 0.5f, 0.f), 1.f); }

union V16 { uint4 u; bf16x8 b; };

// ---------------------------------------------------------------------------
// Fused ConvLSTM step: one block = one (batch b, row y).
// g = conv3x3_SAME([inA | h], Wcat) + bias   (implicit GEMM, MFMA 16x16x32)
// then LSTM gate update: c' = hsig(f)*c + hsig(i)*tanh(g_c); h' = hsig(o)*tanh(c')
// M = 48 pixels, N = 256 gate channels, K = 9*(CIN_A+64).
// 4 waves: each wave all 48 pixels x 64 channels (M_rep=3, N_rep=4).
// ---------------------------------------------------------------------------
template<int CIN_A, int CPAD>
__global__ __launch_bounds__(256) void convlstm_step(
    const ushort* __restrict__ inA, long strideA,   // (B,2304,CIN_A) via stride
    const ushort* __restrict__ inB,                 // h_prev (B,2304,64) bf16
    const ushort* __restrict__ Wsw,                 // swizzled [ntile][KS][64][8]
    const float*  __restrict__ bias,                // (256)
    float*  __restrict__ cState,                    // (B,2304,64) f32, in place
    ushort* __restrict__ hOut,                      // (B,2304,64) bf16
    ushort* __restrict__ seqOut)                    // may be null
{
    constexpr int CIN_TOT = CIN_A + 64;
    constexpr int K  = 9 * CIN_TOT;
    constexpr int KS = (K + 31) / 32;
    constexpr int KP = KS * 32;
    constexpr int PATCHB = 3 * 50 * CPAD * 2;
    constexpr int GBUFB  = 48 * 260 * 4;
    constexpr int SMEMB  = GBUFB > PATCHB ? GBUFB : PATCHB;   // gbuf also absorbs K-tail OOB reads
    __shared__ __align__(16) unsigned char smem[SMEMB];

    const int bid = blockIdx.x, img = bid / 48, y = bid % 48;
    const int tid = threadIdx.x, wid = tid >> 6, l = tid & 63;
    const int lm = l & 15, lk8 = (l >> 4) * 8;

    // ---- stage 3 x 50 x CIN_TOT patch (zero-padded), padded channel stride ----
    const ushort* aBase = inA + (size_t)img * strideA;
    const ushort* bBase = inB + (size_t)img * IMGPIX * 64;
    constexpr int CA8 = CIN_A / 8;
    for (int e = tid; e < 3 * 48 * CA8; e += 256) {           // x/seq channels
        int r = e / (48 * CA8), q = e % (48 * CA8);
        int col = q / CA8, ci0 = (q % CA8) * 8;
        int gy = y + r - 1;
        uint4 v = make_uint4(0, 0, 0, 0);
        if (gy >= 0 && gy < 48)
            v = *(const uint4*)(aBase + ((size_t)gy * 48 + col) * CIN_A + ci0);
        *(uint4*)(smem + (((r * 50 + col + 1) * CPAD) + ci0) * 2) = v;
    }
    for (int e = tid; e < 3 * 48 * 8; e += 256) {             // h channels
        int r = e / (48 * 8), q = e % (48 * 8);
        int col = q / 8, ci0 = (q % 8) * 8;
        int gy = y + r - 1;
        uint4 v = make_uint4(0, 0, 0, 0);
        if (gy >= 0 && gy < 48)
            v = *(const uint4*)(bBase + ((size_t)gy * 48 + col) * 64 + ci0);
        *(uint4*)(smem + (((r * 50 + col + 1) * CPAD) + CIN_A + ci0) * 2) = v;
    }
    for (int e = tid; e < 3 * 2 * (CIN_TOT / 8); e += 256) {  // pad cols 0 and 49
        int r = e / (2 * (CIN_TOT / 8)), q = e % (2 * (CIN_TOT / 8));
        int dc = (q / (CIN_TOT / 8)) ? 49 : 0, ci0 = (q % (CIN_TOT / 8)) * 8;
        *(uint4*)(smem + (((r * 50 + dc) * CPAD) + ci0) * 2) = make_uint4(0, 0, 0, 0);
    }
    __syncthreads();

    f32x4 acc[3][4] = {};

#pragma unroll
    for (int ks = 0; ks < KS; ++ks) {
        V16 bf[4];
#pragma unroll
        for (int nr = 0; nr < 4; ++nr) {
            const int ntile = wid * 4 + nr;
            bf[nr].u = *(const uint4*)(Wsw + ((size_t)((ntile * KS + ks) * 64 + l)) * 8);
        }
        V16 af[3];
#pragma unroll
        for (int m = 0; m < 3; ++m) {
            const int p   = m * 16 + lm;
            const int k   = ks * 32 + lk8;
            const int tap = k / CIN_TOT, ci0 = k % CIN_TOT;
            const int ky  = tap / 3, kx = tap - 3 * (tap / 3);
            const int c   = p + kx;
            uint4 v = *(const uint4*)(smem + (((ky * 50 + c) * CPAD) + ci0) * 2);
            if (KP > K && ks == KS - 1 && k >= K) v = make_uint4(0, 0, 0, 0);
            af[m].u = v;
        }
#pragma unroll
        for (int m = 0; m < 3; ++m)
#pragma unroll
            for (int nr = 0; nr < 4; ++nr)
                acc[m][nr] = __builtin_amdgcn_mfma_f32_16x16x32_bf16(
                    af[m].b, bf[nr].b, acc[m][nr], 0, 0, 0);
    }

    // ---- epilogue: gates -> LSTM state update ----
    __syncthreads();                       // patch region now dead
    float* gbuf = (float*)smem;            // [48][260] f32
#pragma unroll
    for (int m = 0; m < 3; ++m)
#pragma unroll
        for (int nr = 0; nr < 4; ++nr) {
            const int ch = wid * 64 + nr * 16 + lm;
            const float bv = bias[ch];
#pragma unroll
            for (int r = 0; r < 4; ++r) {
                const int pixel = m * 16 + (l >> 4) * 4 + r;
                gbuf[pixel * 260 + ch] = acc[m][nr][r] + bv;
            }
        }
    __syncthreads();
    const size_t base = (size_t)img * IMGPIX + (size_t)y * 48;
    for (int it = 0; it < 12; ++it) {
        const int idx = it * 256 + tid, p = idx >> 6, f = idx & 63;
        const float gi = gbuf[p * 260 + f];
        const float gf = gbuf[p * 260 + 64 + f];
        const float gc = gbuf[p * 260 + 128 + f];
        const float go = gbuf[p * 260 + 192 + f];
        const size_t off = (base + p) * F + f;
        const float cn = hsig(gf) * cState[off] + hsig(gi) * tanhf(gc);
        const float hn = hsig(go) * tanhf(cn);
        cState[off] = cn;
        hOut[off]   = f2b(hn);
        if (seqOut) seqOut[off] = f2b(hn);
    }
}

// ---------------------------------------------------------------------------
// Concatenated-weight reorder: [Wx (3,3,CIN_A,256) ; Wh (3,3,64,256)] fp32
// -> bf16 swizzled [ntile][KS][64][8], zero-padded to KS*32.
// out[((ntile*KS+ks)*64+l)*8+j] = Wcat[k][n], n = ntile*16+(l&15),
// k = ks*32+(l>>4)*8+j, Wcat k-order: tap-major, ci = [x-ch | h-ch].
// ---------------------------------------------------------------------------
template<int CIN_A>
__global__ __launch_bounds__(256) void swizzle_wcat(
    const float* __restrict__ Wx, const float* __restrict__ Wh,
    ushort* __restrict__ out)
{
    constexpr int CIN_TOT = CIN_A + 64;
    constexpr int K  = 9 * CIN_TOT;
    constexpr int KS = (K + 31) / 32;
    const int idx = blockIdx.x * 256 + threadIdx.x;
    if (idx >= 16 * KS * 512) return;
    const int j = idx & 7, l = (idx >> 3) & 63, rest = idx >> 9;
    const int ks = rest % KS, ntile = rest / KS;
    const int n = ntile * 16 + (l & 15);
    const int k = ks * 32 + ((l >> 4) & 3) * 8 + j;
    float v = 0.f;
    if (k < K) {
        const int tap = k / CIN_TOT, ci = k % CIN_TOT;
        v = (ci < CIN_A) ? Wx[((size_t)tap * CIN_A + ci) * CO + n]
                         : Wh[((size_t)tap * 64 + (ci - CIN_A)) * CO + n];
    }
    out[idx] = f2b(v);
}

__global__ __launch_bounds__(256) void cast_f32_bf16(
    const float* __restrict__ src, ushort* __restrict__ dst, long n8)
{
    const long c = (long)blockIdx.x * 256 + threadIdx.x;
    if (c >= n8) return;
    const float4* s = (const float4*)(src + c * 8);
    const float4 a = s[0], b = s[1];
    ushort o[8] = { f2b(a.x), f2b(a.y), f2b(a.z), f2b(a.w),
                    f2b(b.x), f2b(b.y), f2b(b.z), f2b(b.w) };
    *(uint4*)(dst + c * 8) = *(const uint4*)o;
}

// ---------------------------------------------------------------------------
// BatchNorm on bf16 seq: per-channel sum/sumsq -> stats[128], then normalize.
// ---------------------------------------------------------------------------
__global__ __launch_bounds__(256) void bn_reduce(
    const ushort* __restrict__ seq, float* __restrict__ stats)
{
    const int  gtid   = blockIdx.x * 256 + threadIdx.x;
    const long stride = (long)gridDim.x * 256;
    const long NCH    = SEQ_ELEMS / 8;
    float s[8] = {}, s2[8] = {};
    for (long c = gtid; c < NCH; c += stride) {
        const uint4 v = *(const uint4*)(seq + c * 8);
        const ushort* u = (const ushort*)&v;
#pragma unroll
        for (int j = 0; j < 8; ++j) { const float f = b2f(u[j]); s[j] += f; s2[j] += f * f; }
    }
#pragma unroll
    for (int j = 0; j < 8; ++j)
#pragma unroll
        for (int off = 8; off < 64; off <<= 1) {
            s[j]  += __shfl_xor(s[j],  off);
            s2[j] += __shfl_xor(s2[j], off);
        }
    __shared__ float red[4][2][8][8];          // [wave][kind][j][octet]
    const int wid = threadIdx.x >> 6, l = threadIdx.x & 63;
    if (l < 8) {
#pragma unroll
        for (int j = 0; j < 8; ++j) { red[wid][0][j][l] = s[j]; red[wid][1][j][l] = s2[j]; }
    }
    __syncthreads();
    if (threadIdx.x < 128) {
        const int kind = threadIdx.x >> 6, f = threadIdx.x & 63;
        const int oct = f >> 3, j = f & 7;
        const float v = red[0][kind][j][oct] + red[1][kind][j][oct]
                      + red[2][kind][j][oct] + red[3][kind][j][oct];
        atomicAdd(&stats[kind * 64 + f], v);
    }
}

__global__ __launch_bounds__(256) void bn_norm(
    ushort* __restrict__ seq, const float* __restrict__ stats,
    const float* __restrict__ gamma, const float* __restrict__ beta)
{
    const long c = (long)blockIdx.x * 256 + threadIdx.x;   // chunk of 8
    uint4 v = *(uint4*)(seq + c * 8);
    ushort* u = (ushort*)&v;
    const int f0 = (int)(c & 7) * 8;
#pragma unroll
    for (int j = 0; j < 8; ++j) {
        const int f = f0 + j;
        const float mean = stats[f] * BN_INVN;
        const float var  = stats[64 + f] * BN_INVN - mean * mean;
        const float sc   = gamma[f] * rsqrtf(var + 1e-3f);
        const float sh   = beta[f] - mean * sc;
        u[j] = f2b(b2f(u[j]) * sc + sh);
    }
    *(uint4*)(seq + c * 8) = v;
}

__global__ __launch_bounds__(256) void copy_out_kernel(
    const ushort* __restrict__ h1, const float* __restrict__ c1,
    const ushort* __restrict__ h2, const float* __restrict__ c2,
    float* __restrict__ out)
{
    const long idx = (long)blockIdx.x * 256 + threadIdx.x;
    const long S = STATE_ELEMS;
    float v;
    if      (idx <     S) v = b2f(h1[idx]);
    else if (idx < 2 * S) v = c1[idx - S];
    else if (idx < 3 * S) v = b2f(h2[idx - 2 * S]);
    else                  v = c2[idx - 3 * S];
    out[idx] = v;
}

// ---------------------------------------------------------------------------
extern "C" void kernel_launch(void* const* d_in, const int* in_sizes, int n_in,
                              void* d_out, int out_size, void* d_ws, size_t ws_size,
                              hipStream_t stream)
{
    const float* x      = (const float*)d_in[0];
    const float* Wx1    = (const float*)d_in[1];
    const float* Wh1    = (const float*)d_in[2];
    const float* b1     = (const float*)d_in[3];
    const float* gamma1 = (const float*)d_in[4];
    const float* beta1  = (const float*)d_in[5];
    const float* Wx2    = (const float*)d_in[6];
    const float* Wh2    = (const float*)d_in[7];
    const float* b2     = (const float*)d_in[8];

    // workspace layout (bytes) -- total ~49.3 MB (round-3 proved >=85 MB works)
    unsigned char* w = (unsigned char*)d_ws;
    ushort* seq1 = (ushort*)w;  w += 23592960;   // (T,B,2304,64) bf16
    ushort* xb   = (ushort*)w;  w += 5898240;    // (B,T,2304,16) bf16
    ushort* wc1  = (ushort*)w;  w += 376832;     // 16*23*512 u16
    ushort* wc2  = (ushort*)w;  w += 589824;     // 16*36*512 u16
    unsigned char* zbase = w;
    ushort* hb1a = (ushort*)w;  w += 2359296;
    ushort* hb1b = (ushort*)w;  w += 2359296;
    ushort* hb2a = (ushort*)w;  w += 2359296;
    ushort* hb2b = (ushort*)w;  w += 2359296;
    float*  c1   = (float*)w;   w += 4718592;
    float*  c2   = (float*)w;   w += 4718592;
    float*  stats = (float*)w;  w += 512;
    hipMemsetAsync(zbase, 0, (size_t)(4 * 2359296 + 2 * 4718592 + 512), stream);

    cast_f32_bf16<<<1440, 256, 0, stream>>>(x, xb, 368640);
    swizzle_wcat<16><<<736, 256, 0, stream>>>(Wx1, Wh1, wc1);    // K=720, KS=23
    swizzle_wcat<64><<<1152, 256, 0, stream>>>(Wx2, Wh2, wc2);   // K=1152, KS=36

    // ----- layer 1: fused input+recurrent conv + gate update, per timestep -----
    ushort* hp1[2] = { hb1a, hb1b };
    for (int t = 0; t < T; ++t) {
        convlstm_step<16, 88><<<384, 256, 0, stream>>>(
            xb + (size_t)t * IMGPIX * 16, (long)T * IMGPIX * 16,
            hp1[t & 1], wc1, b1, c1, hp1[(t + 1) & 1],
            seq1 + (size_t)t * STATE_ELEMS);
    }

    bn_reduce<<<256, 256, 0, stream>>>(seq1, stats);
    bn_norm<<<5760, 256, 0, stream>>>(seq1, stats, gamma1, beta1);

    // ----- layer 2 -----
    ushort* hp2[2] = { hb2a, hb2b };
    for (int t = 0; t < T; ++t) {
        convlstm_step<64, 136><<<384, 256, 0, stream>>>(
            seq1 + (size_t)t * STATE_ELEMS, IMGPIX * 64,
            hp2[t & 1], wc2, b2, c2, hp2[(t + 1) & 1], nullptr);
    }

    copy_out_kernel<<<18432, 256, 0, stream>>>(hb1a, c1, hb2a, c2, (float*)d_out);
}

// Round 7
// 413.917 us; speedup vs baseline: 10.7238x; 1.0460x over previous
//
#include <hip/hip_runtime.h>
#include <hip/hip_bf16.h>

typedef short bf16x8 __attribute__((ext_vector_type(8)));   // 8 bf16 in 4 VGPRs
typedef float f32x4  __attribute__((ext_vector_type(4)));

constexpr int B = 8, T = 10, F = 64, CO = 256;
constexpr long IMGPIX      = 48 * 48;                // 2304
constexpr long STATE_ELEMS = (long)B * IMGPIX * F;   // 1,179,648
constexpr long SEQ_ELEMS   = (long)T * STATE_ELEMS;  // 11,796,480
constexpr float BN_INVN    = 1.0f / (float)(B * T * IMGPIX);

__device__ __forceinline__ float  b2f(ushort u) { return __uint_as_float(((unsigned)u) << 16); }
__device__ __forceinline__ ushort f2b(float f) {
    unsigned x = __float_as_uint(f);
    return (ushort)((x + 0x7fffu + ((x >> 16) & 1u)) >> 16);   // RNE
}
__device__ __forceinline__ float hsig(float x) { return fminf(fmaxf(0.2f * x + 0.5f, 0.f), 1.f); }
__device__ __forceinline__ float tanh_f(float v) {
    return 1.f - 2.f / (__expf(2.f * v) + 1.f);    // exact at +/-inf, ~1e-6 err
}

union V16 { uint4 u; bf16x8 b; };

// ---------------------------------------------------------------------------
// Fused ConvLSTM step, N-split + K-split version.
// Grid = 768: (img 0..7) x (row y 0..47) x (channel-half h 0..1).
// Block = 256 threads (4 waves). Wave wid: q = 2*half + (wid&1) is its f-tile
// (16 f-channels -> gate ntiles q, q+4, q+8, q+12); kshard = wid>>1 takes
// ks = 2*ksl + kshard (interleaved K split). Partial sums are combined in LDS
// (gbuf), then the block does the LSTM gate update for its 32 f-channels.
// FIRST: h_prev = c_prev = 0 (no reads). STATS: accumulate BN sum/sumsq and
// write seqOut. BNIN: normalize the A-channels while staging (fused BN) --
// ONLY for in-bounds pixels (SAME padding stays zero, as in the reference).
// OUT: also write h (f32) to outF[0..S) and c to outF[S..2S).
// ---------------------------------------------------------------------------
template<int CIN_A, int CPAD, bool FIRST, bool STATS, bool BNIN, bool OUT>
__global__ __launch_bounds__(256, 3) void convlstm_step(
    const ushort* __restrict__ inA, long strideA,   // per-img stride (elements)
    const ushort* __restrict__ inB,                 // h_prev (B,2304,64) bf16
    const ushort* __restrict__ Wsw,                 // swizzled [ntile][KS][64][8]
    const float*  __restrict__ bias,                // (256)
    float*  __restrict__ cState,                    // (B,2304,64) f32 in place
    ushort* __restrict__ hOut,                      // (B,2304,64) bf16
    ushort* __restrict__ seqOut,                    // STATS only
    float*  __restrict__ stats,                     // [128] (STATS: atomic out; BNIN: in)
    const float* __restrict__ gamma,
    const float* __restrict__ beta,
    float*  __restrict__ outF)                      // OUT only
{
    constexpr int CIN_TOT = CIN_A + 64;
    constexpr int K   = 9 * CIN_TOT;
    constexpr int KS  = (K + 31) / 32;
    constexpr int KSH = (KS + 1) / 2;
    constexpr int KP  = KS * 32;
    constexpr int PATCHB = 3 * 50 * CPAD * 2;
    constexpr int SMEMB  = PATCHB > 26368 ? PATCHB : 26368;  // gbuf 25344 + sred 1024
    __shared__ __align__(16) unsigned char smem[SMEMB];
    __shared__ float bnsc[64], bnsh[64];

    const int bid  = blockIdx.x;
    const int img  = bid / 96;
    const int rem  = bid % 96;
    const int y    = rem >> 1;
    const int half = rem & 1;
    const int tid = threadIdx.x, wid = tid >> 6, l = tid & 63;
    const int lm = l & 15, lk8 = (l >> 4) * 8;

    if constexpr (BNIN) {
        if (tid < 64) {
            const float mean = stats[tid] * BN_INVN;
            const float var  = stats[64 + tid] * BN_INVN - mean * mean;
            const float sc   = gamma[tid] * rsqrtf(var + 1e-3f);
            bnsc[tid] = sc;
            bnsh[tid] = beta[tid] - mean * sc;
        }
        __syncthreads();
    }

    // ---- stage 3 x 50 x CIN_TOT patch (zero-padded), padded channel stride ----
    const ushort* aBase = inA + (size_t)img * strideA;
    const ushort* bBase = inB + (size_t)img * IMGPIX * 64;
    constexpr int CA8 = CIN_A / 8;
    for (int e = tid; e < 3 * 48 * CA8; e += 256) {           // x/seq channels
        const int r = e / (48 * CA8), qq = e % (48 * CA8);
        const int col = qq / CA8, ci0 = (qq % CA8) * 8;
        const int gy = y + r - 1;
        uint4 v = make_uint4(0, 0, 0, 0);
        if (gy >= 0 && gy < 48) {
            v = *(const uint4*)(aBase + ((size_t)gy * 48 + col) * CIN_A + ci0);
            if constexpr (BNIN) {      // BN only on real pixels; padding stays 0
                ushort* u = (ushort*)&v;
#pragma unroll
                for (int j = 0; j < 8; ++j)
                    u[j] = f2b(b2f(u[j]) * bnsc[ci0 + j] + bnsh[ci0 + j]);
            }
        }
        *(uint4*)(smem + ((r * 50 + col + 1) * CPAD + ci0) * 2) = v;
    }
    for (int e = tid; e < 3 * 48 * 8; e += 256) {             // h channels
        const int r = e / (48 * 8), qq = e % (48 * 8);
        const int col = qq / 8, ci0 = (qq % 8) * 8;
        uint4 v = make_uint4(0, 0, 0, 0);
        if constexpr (!FIRST) {
            const int gy = y + r - 1;
            if (gy >= 0 && gy < 48)
                v = *(const uint4*)(bBase + ((size_t)gy * 48 + col) * 64 + ci0);
        }
        *(uint4*)(smem + ((r * 50 + col + 1) * CPAD + CIN_A + ci0) * 2) = v;
    }
    constexpr int CT8 = CIN_TOT / 8;
    for (int e = tid; e < 3 * 2 * CT8; e += 256) {            // pad cols 0 and 49
        const int r = e / (2 * CT8), qq = e % (2 * CT8);
        const int dc = (qq / CT8) ? 49 : 0, ci0 = (qq % CT8) * 8;
        *(uint4*)(smem + ((r * 50 + dc) * CPAD + ci0) * 2) = make_uint4(0, 0, 0, 0);
    }
    __syncthreads();

    const int q      = 2 * half + (wid & 1);
    const int kshard = wid >> 1;

    f32x4 acc[3][4] = {};

#pragma unroll
    for (int ksl = 0; ksl < KSH; ++ksl) {
        const int ks = 2 * ksl + kshard;
        if (ks < KS) {
            V16 bf[4];
#pragma unroll
            for (int nr = 0; nr < 4; ++nr) {
                const int ntile = nr * 4 + q;
                bf[nr].u = *(const uint4*)(Wsw + ((size_t)((ntile * KS + ks) * 64) + l) * 8);
            }
            V16 af[3];
#pragma unroll
            for (int m = 0; m < 3; ++m) {
                const int k   = ks * 32 + lk8;
                const int tap = k / CIN_TOT, ci0 = k % CIN_TOT;
                const int ky  = tap / 3, kx = tap - 3 * (tap / 3);
                const int c   = m * 16 + lm + kx;
                uint4 v = *(const uint4*)(smem + ((ky * 50 + c) * CPAD + ci0) * 2);
                if (KP > K && ks == KS - 1 && k >= K) v = make_uint4(0, 0, 0, 0);
                af[m].u = v;
            }
#pragma unroll
            for (int m = 0; m < 3; ++m)
#pragma unroll
                for (int nr = 0; nr < 4; ++nr)
                    acc[m][nr] = __builtin_amdgcn_mfma_f32_16x16x32_bf16(
                        af[m].b, bf[nr].b, acc[m][nr], 0, 0, 0);
        }
    }

    // ---- combine K-shards in LDS, then gate update ----
    __syncthreads();                       // patch region now dead
    float* gbuf = (float*)smem;            // [48][132] f32
    float* sred = (float*)(smem + 25344);  // [4][2][32] f32
    const int fl = (q & 1) * 16 + lm;      // f index within block's 32

    if (kshard == 0) {
#pragma unroll
        for (int nr = 0; nr < 4; ++nr) {
            const float bv = bias[nr * 64 + q * 16 + lm];
#pragma unroll
            for (int m = 0; m < 3; ++m)
#pragma unroll
                for (int r = 0; r < 4; ++r) {
                    const int pixel = m * 16 + (l >> 4) * 4 + r;
                    gbuf[pixel * 132 + nr * 32 + fl] = acc[m][nr][r] + bv;
                }
        }
    }
    __syncthreads();
    if (kshard == 1) {
#pragma unroll
        for (int nr = 0; nr < 4; ++nr)
#pragma unroll
            for (int m = 0; m < 3; ++m)
#pragma unroll
                for (int r = 0; r < 4; ++r) {
                    const int pixel = m * 16 + (l >> 4) * 4 + r;
                    gbuf[pixel * 132 + nr * 32 + fl] += acc[m][nr][r];
                }
    }
    __syncthreads();

    float s1 = 0.f, s2 = 0.f;
    const size_t rowBase = (size_t)img * IMGPIX + (size_t)y * 48;
#pragma unroll
    for (int it = 0; it < 6; ++it) {
        const int idx = it * 256 + tid;
        const int p = idx >> 5, fr = idx & 31;     // fr fixed per thread
        const float gi = gbuf[p * 132 + fr];
        const float gf = gbuf[p * 132 + 32 + fr];
        const float gc = gbuf[p * 132 + 64 + fr];
        const float go = gbuf[p * 132 + 96 + fr];
        const size_t off = (rowBase + p) * 64 + half * 32 + fr;
        const float cold = FIRST ? 0.f : cState[off];
        const float cn = hsig(gf) * cold + hsig(gi) * tanh_f(gc);
        const float hn = hsig(go) * tanh_f(cn);
        cState[off] = cn;
        hOut[off]   = f2b(hn);
        if constexpr (STATS) { seqOut[off] = f2b(hn); s1 += hn; s2 += hn * hn; }
        if constexpr (OUT)   { outF[off] = hn; outF[STATE_ELEMS + off] = cn; }
    }

    if constexpr (STATS) {
        s1 += __shfl_xor(s1, 32);
        s2 += __shfl_xor(s2, 32);
        if (l < 32) { sred[wid * 64 + l] = s1; sred[wid * 64 + 32 + l] = s2; }
        __syncthreads();
        if (tid < 64) {
            const int kind = tid >> 5, fr = tid & 31;
            const float v = sred[kind * 32 + fr] + sred[64 + kind * 32 + fr]
                          + sred[128 + kind * 32 + fr] + sred[192 + kind * 32 + fr];
            atomicAdd(&stats[kind * 64 + half * 32 + fr], v);
        }
    }
}

// ---------------------------------------------------------------------------
// One-shot prep: cast x to bf16, build both swizzled concat weights, zero stats.
// Weight layout: out[((ntile*KS+ks)*64+l)*8+j] = Wcat[k][n], n = ntile*16+(l&15),
// k = ks*32+((l>>4)&3)*8+j; Wcat k-order tap-major, ci = [x-ch | h-ch].
// ---------------------------------------------------------------------------
__device__ __forceinline__ ushort swz_elem(
    const float* __restrict__ Wx, const float* __restrict__ Wh,
    int CIN_A, int KS, int idx)
{
    const int K = 9 * (CIN_A + 64);
    const int j = idx & 7, lw = (idx >> 3) & 63, rest = idx >> 9;
    const int ks = rest % KS, ntile = rest / KS;
    const int n = ntile * 16 + (lw & 15);
    const int k = ks * 32 + ((lw >> 4) & 3) * 8 + j;
    if (k >= K) return (ushort)0;
    const int CT = CIN_A + 64;
    const int tap = k / CT, ci = k % CT;
    const float v = (ci < CIN_A) ? Wx[((size_t)tap * CIN_A + ci) * CO + n]
                                 : Wh[((size_t)tap * 64 + (ci - CIN_A)) * CO + n];
    return f2b(v);
}

__global__ __launch_bounds__(256) void prep_kernel(
    const float* __restrict__ x,
    const float* __restrict__ Wx1, const float* __restrict__ Wh1,
    const float* __restrict__ Wx2, const float* __restrict__ Wh2,
    ushort* __restrict__ xb, ushort* __restrict__ wc1, ushort* __restrict__ wc2,
    float* __restrict__ stats)
{
    constexpr int N0 = 368640;          // x: 2,949,120 elems / 8
    constexpr int N1 = 16 * 23 * 512;   // 188,416
    constexpr int N2 = 16 * 36 * 512;   // 294,912
    const int gid = blockIdx.x * 256 + threadIdx.x;
    if (gid < N0) {
        const float4 a = ((const float4*)x)[(size_t)gid * 2];
        const float4 b = ((const float4*)x)[(size_t)gid * 2 + 1];
        ushort o[8] = { f2b(a.x), f2b(a.y), f2b(a.z), f2b(a.w),
                        f2b(b.x), f2b(b.y), f2b(b.z), f2b(b.w) };
        *(uint4*)(xb + (size_t)gid * 8) = *(const uint4*)o;
    } else if (gid < N0 + N1) {
        wc1[gid - N0] = swz_elem(Wx1, Wh1, 16, 23, gid - N0);
    } else if (gid < N0 + N1 + N2) {
        wc2[gid - N0 - N1] = swz_elem(Wx2, Wh2, 64, 36, gid - N0 - N1);
    } else if (gid < N0 + N1 + N2 + 128) {
        stats[gid - N0 - N1 - N2] = 0.f;
    }
}

// ---------------------------------------------------------------------------
extern "C" void kernel_launch(void* const* d_in, const int* in_sizes, int n_in,
                              void* d_out, int out_size, void* d_ws, size_t ws_size,
                              hipStream_t stream)
{
    const float* x      = (const float*)d_in[0];
    const float* Wx1    = (const float*)d_in[1];
    const float* Wh1    = (const float*)d_in[2];
    const float* b1     = (const float*)d_in[3];
    const float* gamma1 = (const float*)d_in[4];
    const float* beta1  = (const float*)d_in[5];
    const float* Wx2    = (const float*)d_in[6];
    const float* Wh2    = (const float*)d_in[7];
    const float* b2     = (const float*)d_in[8];

    // workspace layout (bytes) -- ~49 MB of the 256 MB ws
    unsigned char* w = (unsigned char*)d_ws;
    ushort* seq1 = (ushort*)w;  w += 23592960;   // (T,B,2304,64) bf16
    ushort* xb   = (ushort*)w;  w += 5898240;    // (B,T,2304,16) bf16
    ushort* wc1  = (ushort*)w;  w += 376832;     // 16*23*512 u16
    ushort* wc2  = (ushort*)w;  w += 589824;     // 16*36*512 u16
    ushort* hb1a = (ushort*)w;  w += 2359296;
    ushort* hb1b = (ushort*)w;  w += 2359296;
    ushort* hb2a = (ushort*)w;  w += 2359296;
    ushort* hb2b = (ushort*)w;  w += 2359296;
    float*  c1   = (float*)w;   w += 4718592;
    float*  c2   = (float*)w;   w += 4718592;
    float*  stats = (float*)w;  w += 512;

    prep_kernel<<<3329, 256, 0, stream>>>(x, Wx1, Wh1, Wx2, Wh2, xb, wc1, wc2, stats);

    const long xStride = (long)T * IMGPIX * 16;
    ushort* hp1[2] = { hb1a, hb1b };

    // ----- layer 1 (STATS: accumulate BN sums; t=9 also writes d_out h1,c1) -----
    convlstm_step<16, 88, true, true, false, false><<<768, 256, 0, stream>>>(
        xb, xStride, hp1[0], wc1, b1, c1, hp1[1],
        seq1, stats, nullptr, nullptr, nullptr);
    for (int t = 1; t < 9; ++t)
        convlstm_step<16, 88, false, true, false, false><<<768, 256, 0, stream>>>(
            xb + (size_t)t * IMGPIX * 16, xStride, hp1[t & 1], wc1, b1, c1, hp1[(t + 1) & 1],
            seq1 + (size_t)t * STATE_ELEMS, stats, nullptr, nullptr, nullptr);
    convlstm_step<16, 88, false, true, false, true><<<768, 256, 0, stream>>>(
        xb + (size_t)9 * IMGPIX * 16, xStride, hp1[1], wc1, b1, c1, hp1[0],
        seq1 + (size_t)9 * STATE_ELEMS, stats, nullptr, nullptr, (float*)d_out);

    // ----- layer 2 (BNIN: normalize seq1 on the fly; t=9 writes d_out h2,c2) -----
    ushort* hp2[2] = { hb2a, hb2b };
    convlstm_step<64, 136, true, false, true, false><<<768, 256, 0, stream>>>(
        seq1, IMGPIX * 64, hp2[0], wc2, b2, c2, hp2[1],
        nullptr, stats, gamma1, beta1, nullptr);
    for (int t = 1; t < 9; ++t)
        convlstm_step<64, 136, false, false, true, false><<<768, 256, 0, stream>>>(
            seq1 + (size_t)t * STATE_ELEMS, IMGPIX * 64, hp2[t & 1], wc2, b2, c2, hp2[(t + 1) & 1],
            nullptr, stats, gamma1, beta1, nullptr);
    convlstm_step<64, 136, false, false, true, true><<<768, 256, 0, stream>>>(
        seq1 + (size_t)9 * STATE_ELEMS, IMGPIX * 64, hp2[1], wc2, b2, c2, hp2[0],
        nullptr, stats, gamma1, beta1, (float*)d_out + 2 * STATE_ELEMS);
}